// Round 8
// baseline (71.867 us; speedup 1.0000x reference)
//
#include <hip/hip_runtime.h>

#define Hdim   128
#define Anodes 512
#define Bbatch 64
#define Eedges 16384
#define AMASK  (Anodes - 1)

// ws float offsets
#define WS_W1T 0                 // bf16[128][128] stored as 8192 floats
#define WS_INV 8192              // f32[512] = 1/max(cnt,1)
#define WS_U   8704              // f32[512][128]

typedef __attribute__((ext_vector_type(8))) short short8;
typedef __attribute__((ext_vector_type(4))) float f32x4;

__device__ __forceinline__ short f2bf(float f) {
    union { float f; unsigned u; } v; v.f = f;
    unsigned r = v.u + 0x7FFFu + ((v.u >> 16) & 1u);
    return (short)(r >> 16);
}

// n1: block 0: cnt hist -> inv_cnt; C = sum_{d:cnt>0} b2.wfc[d]; out[b]=bfc+C
//     blocks 1..4: w1T bf16 strip transpose
__global__ __launch_bounds__(256)
void k_pre(const int* __restrict__ ei, const float* __restrict__ w1,
           const float* __restrict__ wfc, const float* __restrict__ b2,
           const float* __restrict__ bfc, float* __restrict__ ws,
           float* __restrict__ out) {
    __shared__ unsigned cntL[Anodes];
    __shared__ float red[256];
    __shared__ float t[32][129];
    const int tid = threadIdx.x;
    const int blk = blockIdx.x;

    if (blk == 0) {
        for (int i = tid; i < Anodes; i += 256) cntL[i] = 0u;
        __syncthreads();
        #pragma unroll 4
        for (int i = tid; i < Eedges; i += 256)
            atomicAdd(&cntL[ei[Eedges + i] & AMASK], 1u);
        __syncthreads();
        for (int d = tid; d < Anodes; d += 256)
            ws[WS_INV + d] = 1.0f / fmaxf((float)cntL[d], 1.0f);
        // C = b2 . colsum_{d:cnt>0} wfc[d,:]
        const int h = tid & 127, half = tid >> 7;
        float cs = 0.f;
        #pragma unroll 4
        for (int d = half; d < Anodes; d += 2)
            if (cntL[d]) cs += wfc[(size_t)d * Hdim + h];
        red[tid] = cs;
        __syncthreads();
        if (tid < 128) red[tid] = (red[tid] + red[tid + 128]) * b2[tid];
        __syncthreads();
        for (int off = 64; off; off >>= 1) {
            if (tid < off) red[tid] += red[tid + off];
            __syncthreads();
        }
        if (tid < Bbatch) out[tid] = bfc[0] + red[0];
    } else {
        const int k0 = (blk - 1) * 32;
        for (int i = tid; i < 32 * 128; i += 256) {
            int r = i >> 7, c = i & 127;
            t[r][c] = w1[(k0 + r) * Hdim + c];
        }
        __syncthreads();
        short* o = (short*)(ws + WS_W1T);
        const int n = tid >> 1, j0 = (tid & 1) * 16;
        short tmp[16];
        #pragma unroll
        for (int j = 0; j < 16; ++j) tmp[j] = f2bf(t[j0 + j][n]);
        short8* dst = (short8*)(o + n * Hdim + k0 + j0);
        dst[0] = *(short8*)(tmp);
        dst[1] = *(short8*)(tmp + 8);
    }
}

// n2: block s: edge scan (src==s) -> gather G = sum inv_cnt[d]*wfc[d,:]
//     -> U[s,:] = w2 @ G  (f32 exact)
__global__ __launch_bounds__(256)
void k_G(const int* __restrict__ ei, const float* __restrict__ w2,
         const float* __restrict__ wfc, float* __restrict__ ws) {
    __shared__ float w2L[Hdim][Hdim + 1];    // 66 KB, padded
    __shared__ unsigned short dl[Anodes];
    __shared__ float Gr[Hdim];
    __shared__ float gred[Hdim];
    __shared__ int nz;
    const int tid = threadIdx.x;
    const int s = blockIdx.x;

    if (tid == 0) nz = 0;
    __syncthreads();
    // stage w2 (independent of scan)
    for (int i = tid; i < Hdim * Hdim; i += 256)
        w2L[i >> 7][i & 127] = w2[i];
    // scan src half; collect dst of matching edges (multiplicity preserved)
    for (int i = tid; i < Eedges; i += 256) {
        if ((ei[i] & AMASK) == s) {
            int slot = atomicAdd(&nz, 1);
            dl[slot] = (unsigned short)(ei[Eedges + i] & AMASK);
        }
    }
    __syncthreads();

    const int k = tid & 127, half = tid >> 7;
    const int n = nz;
    float g = 0.f;
    for (int i = half; i < n; i += 2) {
        int d = dl[i];
        g += ws[WS_INV + d] * wfc[(size_t)d * Hdim + k];
    }
    if (half) gred[k] = g;
    __syncthreads();
    if (!half) Gr[k] = g + gred[k];
    __syncthreads();

    float u = 0.f;
    const int h0 = half * 64;
    #pragma unroll 8
    for (int hh = h0; hh < h0 + 64; ++hh) u += w2L[k][hh] * Gr[hh];
    if (half) gred[k] = u;
    __syncthreads();
    if (!half) ws[WS_U + (size_t)s * Hdim + k] = u + gred[k];
}

// n3: MFMA; per block 64 rows; out[b] += sum_rows relu(x_row @ w1 + b1) . U[a,:]
__global__ __launch_bounds__(256)
void k_main(const float* __restrict__ x, const float* __restrict__ b1,
            const float* __restrict__ ws, float* __restrict__ out) {
    __shared__ short w1s[Hdim * Hdim];   // swizzled bf16 [n][k], 32 KB
    __shared__ float red[4];

    const int tid  = threadIdx.x;
    const int row0 = blockIdx.x * 64;
    const int b    = blockIdx.x >> 3;
    const int a0   = (blockIdx.x & 7) * 64;

    {
        const short8* gsrc = (const short8*)(ws + WS_W1T);
        for (int i = tid; i < 2048; i += 256) {
            short8 v = gsrc[i];
            int n = i >> 4;
            int byte = (i * 16) ^ ((n & 7) << 4);
            *(short8*)((char*)w1s + byte) = v;
        }
    }
    __syncthreads();

    const int w = tid >> 6;
    const int l = tid & 63;
    const int c = l & 15;
    const int g = l >> 4;

    const float* xrow = x + (size_t)(row0 + w * 16 + c) * Hdim;

    f32x4 acc[8];
    #pragma unroll
    for (int n = 0; n < 8; ++n) acc[n] = (f32x4){0.f, 0.f, 0.f, 0.f};

    #pragma unroll
    for (int ks = 0; ks < 4; ++ks) {
        const int k0 = ks * 32;
        float4 a_lo = *(const float4*)(xrow + k0 + 8 * g);
        float4 a_hi = *(const float4*)(xrow + k0 + 8 * g + 4);
        short8 a;
        a[0] = f2bf(a_lo.x); a[1] = f2bf(a_lo.y); a[2] = f2bf(a_lo.z); a[3] = f2bf(a_lo.w);
        a[4] = f2bf(a_hi.x); a[5] = f2bf(a_hi.y); a[6] = f2bf(a_hi.z); a[7] = f2bf(a_hi.w);
        #pragma unroll
        for (int n = 0; n < 8; ++n) {
            int byte = (((n * 16 + c) << 8) + ((k0 + 8 * g) << 1)) ^ ((c & 7) << 4);
            short8 bf = *(short8*)((char*)w1s + byte);
            acc[n] = __builtin_amdgcn_mfma_f32_16x16x32_bf16(a, bf, acc[n], 0, 0, 0);
        }
    }

    float part = 0.f;
    const float* U = ws + WS_U;
    #pragma unroll
    for (int n = 0; n < 8; ++n) {
        const int colg = n * 16 + c;
        const float bv = b1[colg];
        #pragma unroll
        for (int r = 0; r < 4; ++r) {
            const int arow = a0 + w * 16 + g * 4 + r;
            float z = acc[n][r] + bv;
            part += fmaxf(z, 0.f) * U[arow * Hdim + colg];
        }
    }
    #pragma unroll
    for (int off = 32; off; off >>= 1) part += __shfl_down(part, off, 64);
    if (l == 0) red[w] = part;
    __syncthreads();
    if (tid == 0) atomicAdd(out + b, red[0] + red[1] + red[2] + red[3]);
}

extern "C" void kernel_launch(void* const* d_in, const int* in_sizes, int n_in,
                              void* d_out, int out_size, void* d_ws, size_t ws_size,
                              hipStream_t stream) {
    const float* x   = (const float*)d_in[0];
    // d_in[1] = pos (unused)
    const int*   ei  = (const int*)d_in[2];
    const float* w1  = (const float*)d_in[3];
    const float* b1  = (const float*)d_in[4];
    const float* w2  = (const float*)d_in[5];
    const float* b2  = (const float*)d_in[6];
    const float* wfc = (const float*)d_in[7];
    const float* bfc = (const float*)d_in[8];
    float* out = (float*)d_out;
    float* ws  = (float*)d_ws;

    hipLaunchKernelGGL(k_pre,  dim3(5),   dim3(256), 0, stream, ei, w1, wfc, b2, bfc, ws, out);
    hipLaunchKernelGGL(k_G,    dim3(512), dim3(256), 0, stream, ei, w2, wfc, ws);
    hipLaunchKernelGGL(k_main, dim3(512), dim3(256), 0, stream, x, b1, ws, out);
}

// Round 9
// 34.711 us; speedup vs baseline: 2.0704x; 2.0704x over previous
//
#include <hip/hip_runtime.h>

#define Hdim   128
#define Anodes 512
#define Bbatch 64
#define Eedges 16384
#define AMASK  (Anodes - 1)

// ws float offsets
#define WS_W1T  0        // bf16[128][128] stored as 8192 floats
#define WS_U    8192     // f32[512][128]
#define WS_CARR 73728    // f32[512] per-node C contribution
#define WS_PB   74240    // f32[64] per-batch partials (zeroed in n1)

typedef __attribute__((ext_vector_type(8))) short short8;
typedef __attribute__((ext_vector_type(4))) float f32x4;

__device__ __forceinline__ short f2bf(float f) {
    union { float f; unsigned u; } v; v.f = f;
    unsigned r = v.u + 0x7FFFu + ((v.u >> 16) & 1u);
    return (short)(r >> 16);
}

// n1: blocks 0..511 (s): self-contained per-source aggregation:
//       scan1: dl[] = dst list of edges with src==s; flag[dst]=1
//       scan2: cntL[d] = #dst-occurrences for flagged d; sawS = s appears as dst
//       G = sum_i wfc[dl_i,:]/max(cnt,1);  U[s,:] = w2 @ G;  c[s] = sawS? b2.wfc[s,:] : 0
//     blocks 512..515: w1 -> bf16 w1T strip transpose
//     block 516: zero WS_PB
__global__ __launch_bounds__(256)
void k_G(const int* __restrict__ ei, const float* __restrict__ w1,
         const float* __restrict__ w2, const float* __restrict__ wfc,
         const float* __restrict__ b2, float* __restrict__ ws) {
    __shared__ float w2L[Hdim][Hdim + 1];   // 66 KB (also transpose tile)
    __shared__ unsigned short dl[1024];
    __shared__ unsigned flag[Anodes];
    __shared__ unsigned cntL[Anodes];
    __shared__ float plist[1024];
    __shared__ float Gr[Hdim];
    __shared__ float gred[Hdim];
    __shared__ int nz;
    __shared__ int sawS;

    const int tid = threadIdx.x;
    const int s = blockIdx.x;

    if (s >= Anodes) {
        if (s < Anodes + 4) {                // w1T strips
            const int k0 = (s - Anodes) * 32;
            for (int i = tid; i < 32 * 128; i += 256) {
                int r = i >> 7, c = i & 127;
                w2L[r][c] = w1[(k0 + r) * Hdim + c];
            }
            __syncthreads();
            short* o = (short*)(ws + WS_W1T);
            const int n = tid >> 1, j0 = (tid & 1) * 16;
            short tmp[16];
            #pragma unroll
            for (int j = 0; j < 16; ++j) tmp[j] = f2bf(w2L[j0 + j][n]);
            short8* dst = (short8*)(o + n * Hdim + k0 + j0);
            dst[0] = *(short8*)(tmp);
            dst[1] = *(short8*)(tmp + 8);
        } else {                             // zero partials
            if (tid < Bbatch) ws[WS_PB + tid] = 0.f;
        }
        return;
    }

    for (int i = tid; i < Anodes; i += 256) { flag[i] = 0u; cntL[i] = 0u; }
    if (tid == 0) { nz = 0; sawS = 0; }
    __syncthreads();

    // stage w2 (no dependency on scans)
    for (int i = tid; i < Hdim * Hdim; i += 256)
        w2L[i >> 7][i & 127] = w2[i];

    const int4* s4 = (const int4*)ei;
    const int4* d4 = (const int4*)(ei + Eedges);
    // scan 1: collect dst's of edges with src==s
    for (int i = tid; i < Eedges / 4; i += 256) {
        int4 sv = s4[i];
        int4 dv = d4[i];
        int d;
        if ((sv.x & AMASK) == s) { d = dv.x & AMASK; dl[atomicAdd(&nz, 1)] = (unsigned short)d; flag[d] = 1u; }
        if ((sv.y & AMASK) == s) { d = dv.y & AMASK; dl[atomicAdd(&nz, 1)] = (unsigned short)d; flag[d] = 1u; }
        if ((sv.z & AMASK) == s) { d = dv.z & AMASK; dl[atomicAdd(&nz, 1)] = (unsigned short)d; flag[d] = 1u; }
        if ((sv.w & AMASK) == s) { d = dv.w & AMASK; dl[atomicAdd(&nz, 1)] = (unsigned short)d; flag[d] = 1u; }
    }
    __syncthreads();
    // scan 2: count flagged dst's; detect s as dst
    for (int i = tid; i < Eedges / 4; i += 256) {
        int4 dv = d4[i];
        int d;
        d = dv.x & AMASK; if (flag[d]) atomicAdd(&cntL[d], 1u); if (d == s) sawS = 1;
        d = dv.y & AMASK; if (flag[d]) atomicAdd(&cntL[d], 1u); if (d == s) sawS = 1;
        d = dv.z & AMASK; if (flag[d]) atomicAdd(&cntL[d], 1u); if (d == s) sawS = 1;
        d = dv.w & AMASK; if (flag[d]) atomicAdd(&cntL[d], 1u); if (d == s) sawS = 1;
    }
    __syncthreads();
    const int n = nz;
    for (int i = tid; i < n; i += 256)
        plist[i] = 1.0f / fmaxf((float)cntL[dl[i]], 1.0f);
    __syncthreads();

    const int k = tid & 127, half = tid >> 7;
    float g = 0.f;
    for (int i = half; i < n; i += 2)
        g += plist[i] * wfc[(size_t)dl[i] * Hdim + k];
    if (half) gred[k] = g;
    __syncthreads();
    if (!half) Gr[k] = g + gred[k];
    __syncthreads();

    // U[s,k] = sum_h w2[k,h] * Gr[h]  (f32 exact)
    float u = 0.f;
    const int h0 = half * 64;
    #pragma unroll 8
    for (int hh = h0; hh < h0 + 64; ++hh) u += w2L[k][hh] * Gr[hh];
    if (half) gred[k] = u;
    __syncthreads();
    if (!half) ws[WS_U + (size_t)s * Hdim + k] = u + gred[k];

    // c[s] = sawS ? b2 . wfc[s,:] : 0
    float cv = 0.f;
    if (tid < 128) cv = b2[tid] * wfc[(size_t)s * Hdim + tid];
    #pragma unroll
    for (int off = 32; off; off >>= 1) cv += __shfl_down(cv, off, 64);
    __syncthreads();            // gred free for reuse
    if (tid == 0)  gred[0] = cv;
    if (tid == 64) gred[1] = cv;
    __syncthreads();
    if (tid == 0) ws[WS_CARR + s] = sawS ? (gred[0] + gred[1]) : 0.f;
}

// n2: MFMA; block (b, chunk): partial = sum_{64 rows} relu(x@w1+b1).U + sum c[chunk]
//     (+ bfc for chunk 0); atomicAdd into zeroed ws[WS_PB + b]
__global__ __launch_bounds__(256)
void k_main(const float* __restrict__ x, const float* __restrict__ b1,
            const float* __restrict__ bfc, float* __restrict__ ws) {
    __shared__ short w1s[Hdim * Hdim];   // swizzled bf16 [n][k], 32 KB
    __shared__ float red[4];

    const int tid  = threadIdx.x;
    const int row0 = blockIdx.x * 64;
    const int b    = blockIdx.x >> 3;
    const int a0   = (blockIdx.x & 7) * 64;

    {
        const short8* gsrc = (const short8*)(ws + WS_W1T);
        for (int i = tid; i < 2048; i += 256) {
            short8 v = gsrc[i];
            int n = i >> 4;
            int byte = (i * 16) ^ ((n & 7) << 4);
            *(short8*)((char*)w1s + byte) = v;
        }
    }
    __syncthreads();

    const int w = tid >> 6;
    const int l = tid & 63;
    const int c = l & 15;
    const int g = l >> 4;

    const float* xrow = x + (size_t)(row0 + w * 16 + c) * Hdim;

    f32x4 acc[8];
    #pragma unroll
    for (int n = 0; n < 8; ++n) acc[n] = (f32x4){0.f, 0.f, 0.f, 0.f};

    #pragma unroll
    for (int ks = 0; ks < 4; ++ks) {
        const int k0 = ks * 32;
        float4 a_lo = *(const float4*)(xrow + k0 + 8 * g);
        float4 a_hi = *(const float4*)(xrow + k0 + 8 * g + 4);
        short8 a;
        a[0] = f2bf(a_lo.x); a[1] = f2bf(a_lo.y); a[2] = f2bf(a_lo.z); a[3] = f2bf(a_lo.w);
        a[4] = f2bf(a_hi.x); a[5] = f2bf(a_hi.y); a[6] = f2bf(a_hi.z); a[7] = f2bf(a_hi.w);
        #pragma unroll
        for (int n = 0; n < 8; ++n) {
            int byte = (((n * 16 + c) << 8) + ((k0 + 8 * g) << 1)) ^ ((c & 7) << 4);
            short8 bf = *(short8*)((char*)w1s + byte);
            acc[n] = __builtin_amdgcn_mfma_f32_16x16x32_bf16(a, bf, acc[n], 0, 0, 0);
        }
    }

    float part = 0.f;
    const float* U = ws + WS_U;
    #pragma unroll
    for (int n = 0; n < 8; ++n) {
        const int colg = n * 16 + c;
        const float bv = b1[colg];
        #pragma unroll
        for (int r = 0; r < 4; ++r) {
            const int arow = a0 + w * 16 + g * 4 + r;
            float z = acc[n][r] + bv;
            part += fmaxf(z, 0.f) * U[arow * Hdim + colg];
        }
    }
    #pragma unroll
    for (int off = 32; off; off >>= 1) part += __shfl_down(part, off, 64);
    if (l == 0) red[w] = part;
    __syncthreads();

    // fold per-chunk C contribution (+bfc once per b)
    float cw = 0.f;
    if (tid < 64) cw = ws[WS_CARR + a0 + tid];
    #pragma unroll
    for (int off = 32; off; off >>= 1) cw += __shfl_down(cw, off, 64);
    if (tid == 0) {
        float v = red[0] + red[1] + red[2] + red[3] + cw;
        if (a0 == 0) v += bfc[0];
        atomicAdd(ws + WS_PB + b, v);
    }
}

// n3: publish
__global__ void k_out(const float* __restrict__ ws, float* __restrict__ out) {
    if (threadIdx.x < Bbatch) out[threadIdx.x] = ws[WS_PB + threadIdx.x];
}

extern "C" void kernel_launch(void* const* d_in, const int* in_sizes, int n_in,
                              void* d_out, int out_size, void* d_ws, size_t ws_size,
                              hipStream_t stream) {
    const float* x   = (const float*)d_in[0];
    // d_in[1] = pos (unused)
    const int*   ei  = (const int*)d_in[2];
    const float* w1  = (const float*)d_in[3];
    const float* b1  = (const float*)d_in[4];
    const float* w2  = (const float*)d_in[5];
    const float* b2  = (const float*)d_in[6];
    const float* wfc = (const float*)d_in[7];
    const float* bfc = (const float*)d_in[8];
    float* out = (float*)d_out;
    float* ws  = (float*)d_ws;

    hipLaunchKernelGGL(k_G,    dim3(517), dim3(256), 0, stream, ei, w1, w2, wfc, b2, ws);
    hipLaunchKernelGGL(k_main, dim3(512), dim3(256), 0, stream, x, b1, bfc, ws);
    hipLaunchKernelGGL(k_out,  dim3(1),   dim3(64),  0, stream, ws, out);
}